// Round 1
// baseline (948.074 us; speedup 1.0000x reference)
//
#include <hip/hip_runtime.h>

#define NG    1024
#define NN    64
#define NE    128
#define NH    8
#define ND    32
#define INDIM 256
#define NS_   48
#define EPS_  1e-6

__global__ __launch_bounds__(256, 2) void raal_fused_kernel(
    const float* __restrict__ h,
    const float* __restrict__ Wq, const float* __restrict__ bq,
    const float* __restrict__ Wk, const float* __restrict__ bk,
    const float* __restrict__ Wv, const float* __restrict__ bv,
    const int*   __restrict__ src, const int* __restrict__ dst,
    const int*   __restrict__ ns,
    float* __restrict__ out)
{
  const int g   = blockIdx.x;   // graph
  const int hd  = blockIdx.y;   // head
  const int tid = threadIdx.x;

  // k-major Q,K for conflict-free stage-2 outer product; V row-major for stage 4
  __shared__ float QT[32][68];
  __shared__ float KT[32][68];
  __shared__ float Vs[64][32];
  __shared__ union {
    struct { float hT[32][68]; float wT[32][100]; } st; // GEMM tiles (stage 1)
    float QK[64][65];                                   // score matrix (stage 2+)
  } u;
  __shared__ float  score_s[NE];
  __shared__ int    src_s[NE], dst_s[NE];
  __shared__ double z_s[NN];

  const int ty = tid >> 4, tx = tid & 15;
  const int r0 = ty * 4;        // 4 rows / thread
  const int c0 = tx * 6;        // 6 cols / thread (96 = Q|K|V of 32 each)

  // ---------------- Stage 1: GEMM  [64 x 96] = h_g[64x256] @ W[256x96] ----------------
  float acc[4][6];
  #pragma unroll
  for (int i = 0; i < 4; ++i)
    #pragma unroll
    for (int j = 0; j < 6; ++j) acc[i][j] = 0.f;

  const int lr = tid >> 2;           // 0..63: h row to load
  const int lk = (tid & 3) * 8;      // k offset within chunk
  const int wkk = tid >> 3;          // 0..31: W k-row
  const int wcc = (tid & 7) * 4;     // col base within 32

  for (int kc = 0; kc < 8; ++kc) {
    const int k0 = kc * 32;
    const float* hp = h + ((size_t)(g * NN + lr)) * INDIM + k0 + lk;
    float4 hv0 = *(const float4*)hp;
    float4 hv1 = *(const float4*)(hp + 4);
    const size_t wrow = (size_t)(k0 + wkk) * (NH * ND) + (size_t)hd * ND + wcc;
    float4 wq4 = *(const float4*)(Wq + wrow);
    float4 wk4 = *(const float4*)(Wk + wrow);
    float4 wv4 = *(const float4*)(Wv + wrow);

    __syncthreads();   // previous iteration's readers done
    u.st.hT[lk + 0][lr] = hv0.x; u.st.hT[lk + 1][lr] = hv0.y;
    u.st.hT[lk + 2][lr] = hv0.z; u.st.hT[lk + 3][lr] = hv0.w;
    u.st.hT[lk + 4][lr] = hv1.x; u.st.hT[lk + 5][lr] = hv1.y;
    u.st.hT[lk + 6][lr] = hv1.z; u.st.hT[lk + 7][lr] = hv1.w;
    *(float4*)&u.st.wT[wkk][ 0 + wcc] = wq4;
    *(float4*)&u.st.wT[wkk][32 + wcc] = wk4;
    *(float4*)&u.st.wT[wkk][64 + wcc] = wv4;
    __syncthreads();

    #pragma unroll
    for (int k = 0; k < 32; ++k) {
      float4 a = *(const float4*)&u.st.hT[k][r0];
      float b[6];
      #pragma unroll
      for (int j = 0; j < 6; ++j) b[j] = u.st.wT[k][c0 + j];
      #pragma unroll
      for (int j = 0; j < 6; ++j) {
        acc[0][j] += a.x * b[j];
        acc[1][j] += a.y * b[j];
        acc[2][j] += a.z * b[j];
        acc[3][j] += a.w * b[j];
      }
    }
  }

  // epilogue: + bias, scatter into QT/KT (k-major) and Vs (row-major)
  #pragma unroll
  for (int j = 0; j < 6; ++j) {
    const int c  = c0 + j;
    const int cc = c & 31;
    const float* bias = (c < 32) ? bq : (c < 64) ? bk : bv;
    const float bval = bias[hd * ND + cc];
    #pragma unroll
    for (int i = 0; i < 4; ++i) {
      const int r = r0 + i;
      const float val = acc[i][j] + bval;
      if (c < 32)       QT[cc][r] = val;
      else if (c < 64)  KT[cc][r] = val;
      else              Vs[r][cc] = val;
    }
  }
  __syncthreads();

  // ---------------- Stage 2: QK[s][t] = clip(Q[s]·K[t], -5, 5) ----------------
  {
    const int s0 = ty * 4, t0 = tx * 4;
    float qk[4][4];
    #pragma unroll
    for (int i = 0; i < 4; ++i)
      #pragma unroll
      for (int j = 0; j < 4; ++j) qk[i][j] = 0.f;
    #pragma unroll
    for (int k = 0; k < 32; ++k) {
      float4 qa = *(const float4*)&QT[k][s0];
      float4 kb = *(const float4*)&KT[k][t0];
      qk[0][0] += qa.x * kb.x; qk[0][1] += qa.x * kb.y; qk[0][2] += qa.x * kb.z; qk[0][3] += qa.x * kb.w;
      qk[1][0] += qa.y * kb.x; qk[1][1] += qa.y * kb.y; qk[1][2] += qa.y * kb.z; qk[1][3] += qa.y * kb.w;
      qk[2][0] += qa.z * kb.x; qk[2][1] += qa.z * kb.y; qk[2][2] += qa.z * kb.z; qk[2][3] += qa.z * kb.w;
      qk[3][0] += qa.w * kb.x; qk[3][1] += qa.w * kb.y; qk[3][2] += qa.w * kb.z; qk[3][3] += qa.w * kb.w;
    }
    #pragma unroll
    for (int i = 0; i < 4; ++i)
      #pragma unroll
      for (int j = 0; j < 4; ++j) {
        float v = qk[i][j];
        v = fminf(5.f, fmaxf(-5.f, v));
        u.QK[s0 + i][t0 + j] = v;   // union reuse: GEMM tiles dead (synced above)
      }
  }
  __syncthreads();

  // ---------------- Stage 3: per-edge score ----------------
  if (tid < NE) {
    const int e = tid;
    const int s = src[e], d = dst[e];
    src_s[e] = s; dst_s[e] = d;
    const float num = u.QK[s][d];
    double den = 0.0;
    const int* np_ = ns + (size_t)e * NS_;
    #pragma unroll
    for (int j = 0; j < NS_; ++j) den += (double)u.QK[s][np_[j]];
    score_s[e] = (float)((double)num / (den + (double)EPS_));
  }
  __syncthreads();

  // ---------------- Stage 4: segment sums + output ----------------
  if (tid < NN) {
    double zz = 0.0;
    for (int e = 0; e < NE; ++e)
      if (dst_s[e] == tid) zz += (double)score_s[e];
    z_s[tid] = zz;
  }

  const int d  = tid & 31;   // feature dim
  const int nb = tid >> 5;   // node block: handles n = nb*8 .. nb*8+7
  float wv[8];
  #pragma unroll
  for (int i = 0; i < 8; ++i) wv[i] = 0.f;
  for (int e = 0; e < NE; ++e) {
    const int   de = dst_s[e];
    const float sc = score_s[e];
    const float vd = Vs[src_s[e]][d];
    const float p  = sc * vd;
    const int   rel = de - nb * 8;
    #pragma unroll
    for (int i = 0; i < 8; ++i) wv[i] += (rel == i) ? p : 0.f;
  }
  __syncthreads();

  #pragma unroll
  for (int i = 0; i < 8; ++i) {
    const int n = nb * 8 + i;
    const double zz = z_s[n] + (double)EPS_;
    out[(((size_t)(g * NN + n)) * NH + hd) * ND + d] = (float)((double)wv[i] / zz);
  }
}

extern "C" void kernel_launch(void* const* d_in, const int* in_sizes, int n_in,
                              void* d_out, int out_size, void* d_ws, size_t ws_size,
                              hipStream_t stream) {
  const float* h   = (const float*)d_in[0];
  const float* Wq  = (const float*)d_in[1];
  const float* bq  = (const float*)d_in[2];
  const float* Wk  = (const float*)d_in[3];
  const float* bk  = (const float*)d_in[4];
  const float* Wv  = (const float*)d_in[5];
  const float* bv  = (const float*)d_in[6];
  const int*   src = (const int*)d_in[7];
  const int*   dst = (const int*)d_in[8];
  const int*   ns  = (const int*)d_in[9];
  float* out = (float*)d_out;

  dim3 grid(NG, NH, 1);
  dim3 block(256, 1, 1);
  hipLaunchKernelGGL(raal_fused_kernel, grid, block, 0, stream,
                     h, Wq, bq, Wk, bk, Wv, bv, src, dst, ns, out);
}

// Round 2
// 761.808 us; speedup vs baseline: 1.2445x; 1.2445x over previous
//
#include <hip/hip_runtime.h>

#define NG    1024
#define NN    64
#define NE    128
#define NH    8
#define ND    32
#define INDIM 256
#define NS_   48
#define EPS_  1e-6
#define BK    16

__global__ __launch_bounds__(256, 4) void raal_fused_kernel(
    const float* __restrict__ h,
    const float* __restrict__ Wq, const float* __restrict__ bq,
    const float* __restrict__ Wk, const float* __restrict__ bk,
    const float* __restrict__ Wv, const float* __restrict__ bv,
    const int*   __restrict__ src, const int* __restrict__ dst,
    const int*   __restrict__ ns,
    float* __restrict__ out)
{
  const int hd  = blockIdx.x;   // head (fast dim -> 8 consecutive blocks share h tile in L2)
  const int g   = blockIdx.y;   // graph
  const int tid = threadIdx.x;
  const int ty  = tid >> 4, tx = tid & 15;

  // Q/K k-major for stage 2; region reused as QK for stages 2-4.
  __shared__ union {
    struct { float QT[32][64]; float KT[32][64]; } s2;  // 16384 B
    float QK[64][64];                                   // 16384 B
  } uQ;
  __shared__ float Vs[64][32];                          // 8192 B
  // GEMM staging tiles; region reused for stage-3/4 scratch.
  __shared__ union {
    struct { float hT[BK][68]; float wT[BK][100]; } s1; // 10752 B
    struct { float score[NE]; int srcs[NE]; int dsts[NE];
             double z[NN]; unsigned short elist[NN][64]; int cnt[NN]; } s3; // 10496 B
  } uA;
  // total: 16384 + 8192 + 10752 = 35328 B  -> 4 blocks/CU

  // ---------------- Stage 1: [64 x 96] = h_g[64x256] @ W[256x96] ----------------
  // Thread tile: rows r0..r0+3; Q/K cols c4..c4+3 (0..63); V cols 64+cv..+1.
  const int r0 = ty * 4;
  const int c4 = tx * 4;        // 0..60 over Q(0..31)|K(32..63)
  const int cv = tx * 2;        // 0..30 within V

  float accqk[4][4], accv[4][2];
  #pragma unroll
  for (int i = 0; i < 4; ++i) {
    #pragma unroll
    for (int j = 0; j < 4; ++j) accqk[i][j] = 0.f;
    accv[i][0] = 0.f; accv[i][1] = 0.f;
  }

  // Loader mapping
  const int lr  = tid >> 2;            // h row 0..63
  const int lk4 = (tid & 3) * 4;       // 4 consecutive k per thread
  const int wr  = ty;                  // W row within chunk (0..15)
  const int wc  = tx * 2;              // col pair within head slice
  const float* hrow = h + ((size_t)(g * NN + lr)) * INDIM + lk4;
  const size_t wcol = (size_t)hd * ND + wc;

  float4 hv; float2 wq2, wk2, wv2;
  {
    hv  = *(const float4*)(hrow);
    const size_t wro = (size_t)wr * (NH * ND) + wcol;
    wq2 = *(const float2*)(Wq + wro);
    wk2 = *(const float2*)(Wk + wro);
    wv2 = *(const float2*)(Wv + wro);
  }

  for (int kc = 0; kc < INDIM / BK; ++kc) {
    __syncthreads();   // previous chunk's readers done
    uA.s1.hT[lk4 + 0][lr] = hv.x;
    uA.s1.hT[lk4 + 1][lr] = hv.y;
    uA.s1.hT[lk4 + 2][lr] = hv.z;
    uA.s1.hT[lk4 + 3][lr] = hv.w;
    *(float2*)&uA.s1.wT[wr][ 0 + wc] = wq2;
    *(float2*)&uA.s1.wT[wr][32 + wc] = wk2;
    *(float2*)&uA.s1.wT[wr][64 + wc] = wv2;
    __syncthreads();

    // prefetch next chunk while computing this one
    if (kc + 1 < INDIM / BK) {
      const int k0n = (kc + 1) * BK;
      hv  = *(const float4*)(hrow + k0n);
      const size_t wro = (size_t)(k0n + wr) * (NH * ND) + wcol;
      wq2 = *(const float2*)(Wq + wro);
      wk2 = *(const float2*)(Wk + wro);
      wv2 = *(const float2*)(Wv + wro);
    }

    #pragma unroll
    for (int k = 0; k < BK; ++k) {
      float4 a  = *(const float4*)&uA.s1.hT[k][r0];
      float4 b  = *(const float4*)&uA.s1.wT[k][c4];
      float2 bv2 = *(const float2*)&uA.s1.wT[k][64 + cv];
      #pragma unroll
      for (int i = 0; i < 4; ++i) {
        const float ai = (i == 0) ? a.x : (i == 1) ? a.y : (i == 2) ? a.z : a.w;
        accqk[i][0] += ai * b.x;
        accqk[i][1] += ai * b.y;
        accqk[i][2] += ai * b.z;
        accqk[i][3] += ai * b.w;
        accv[i][0]  += ai * bv2.x;
        accv[i][1]  += ai * bv2.y;
      }
    }
  }

  // Epilogue: + bias, scatter to QT/KT (k-major) and Vs (row-major).
  {
    if (tx < 8) {
      #pragma unroll
      for (int j = 0; j < 4; ++j) {
        const int c = c4 + j;                 // Q col 0..31
        const float b = bq[hd * ND + c];
        #pragma unroll
        for (int i = 0; i < 4; ++i) uQ.s2.QT[c][r0 + i] = accqk[i][j] + b;
      }
    } else {
      #pragma unroll
      for (int j = 0; j < 4; ++j) {
        const int c = c4 - 32 + j;            // K col 0..31
        const float b = bk[hd * ND + c];
        #pragma unroll
        for (int i = 0; i < 4; ++i) uQ.s2.KT[c][r0 + i] = accqk[i][j] + b;
      }
    }
    const float b0 = bv[hd * ND + cv], b1 = bv[hd * ND + cv + 1];
    #pragma unroll
    for (int i = 0; i < 4; ++i) {
      Vs[r0 + i][cv]     = accv[i][0] + b0;
      Vs[r0 + i][cv + 1] = accv[i][1] + b1;
    }
  }
  __syncthreads();

  // ---------------- Stage 2: QK[s][t] = clip(Q[s]·K[t], -5, 5) ----------------
  {
    const int s0 = ty * 4, t0 = tx * 4;
    float qk[4][4];
    #pragma unroll
    for (int i = 0; i < 4; ++i)
      #pragma unroll
      for (int j = 0; j < 4; ++j) qk[i][j] = 0.f;
    #pragma unroll
    for (int k = 0; k < ND; ++k) {
      float4 qa = *(const float4*)&uQ.s2.QT[k][s0];
      float4 kb = *(const float4*)&uQ.s2.KT[k][t0];
      qk[0][0] += qa.x * kb.x; qk[0][1] += qa.x * kb.y; qk[0][2] += qa.x * kb.z; qk[0][3] += qa.x * kb.w;
      qk[1][0] += qa.y * kb.x; qk[1][1] += qa.y * kb.y; qk[1][2] += qa.y * kb.z; qk[1][3] += qa.y * kb.w;
      qk[2][0] += qa.z * kb.x; qk[2][1] += qa.z * kb.y; qk[2][2] += qa.z * kb.z; qk[2][3] += qa.z * kb.w;
      qk[3][0] += qa.w * kb.x; qk[3][1] += qa.w * kb.y; qk[3][2] += qa.w * kb.z; qk[3][3] += qa.w * kb.w;
    }
    __syncthreads();   // all QT/KT reads complete before QK overwrites the region
    #pragma unroll
    for (int i = 0; i < 4; ++i)
      #pragma unroll
      for (int j = 0; j < 4; ++j) {
        float v = qk[i][j];
        v = fminf(5.f, fmaxf(-5.f, v));
        uQ.QK[s0 + i][t0 + j] = v;
      }
  }
  __syncthreads();

  // ---------------- Stage 3: per-edge score ----------------
  if (tid < NE) {
    const int e = tid;
    const int s = src[e], dd = dst[e];
    uA.s3.srcs[e] = s; uA.s3.dsts[e] = dd;
    const float num = uQ.QK[s][dd];
    double den = 0.0;
    const int* np_ = ns + (size_t)e * NS_;
    #pragma unroll
    for (int j = 0; j < NS_; ++j) den += (double)uQ.QK[s][np_[j]];
    uA.s3.score[e] = (float)((double)num / (den + (double)EPS_));
  }
  __syncthreads();

  // ---------------- Stage 3.5: per-node edge list + z (1 wave) ----------------
  if (tid < NN) {
    int c = 0; double zz = 0.0;
    for (int e = 0; e < NE; ++e) {
      if (uA.s3.dsts[e] == tid) {
        zz += (double)uA.s3.score[e];           // e-ascending: bit-exact chain
        if (c < 64) uA.s3.elist[tid][c] = (unsigned short)e;
        ++c;
      }
    }
    uA.s3.cnt[tid] = (c > 64) ? 64 : c;
    uA.s3.z[tid]   = zz;
  }
  __syncthreads();

  // ---------------- Stage 4: weighted segment sum + output ----------------
  {
    const int n  = tid >> 2;
    const int d0 = (tid & 3) * 8;
    float wvv[8];
    #pragma unroll
    for (int i = 0; i < 8; ++i) wvv[i] = 0.f;
    const int cn = uA.s3.cnt[n];
    for (int c = 0; c < cn; ++c) {
      const int e  = uA.s3.elist[n][c];
      const float sc = uA.s3.score[e];
      const int s  = uA.s3.srcs[e];
      float4 v0 = *(const float4*)&Vs[s][d0];
      float4 v1 = *(const float4*)&Vs[s][d0 + 4];
      wvv[0] += sc * v0.x; wvv[1] += sc * v0.y; wvv[2] += sc * v0.z; wvv[3] += sc * v0.w;
      wvv[4] += sc * v1.x; wvv[5] += sc * v1.y; wvv[6] += sc * v1.z; wvv[7] += sc * v1.w;
    }
    const double zz = uA.s3.z[n] + (double)EPS_;
    float o[8];
    #pragma unroll
    for (int i = 0; i < 8; ++i) o[i] = (float)((double)wvv[i] / zz);
    float* op = out + (((size_t)(g * NN + n)) * NH + hd) * ND + d0;
    *(float4*)(op)     = make_float4(o[0], o[1], o[2], o[3]);
    *(float4*)(op + 4) = make_float4(o[4], o[5], o[6], o[7]);
  }
}

extern "C" void kernel_launch(void* const* d_in, const int* in_sizes, int n_in,
                              void* d_out, int out_size, void* d_ws, size_t ws_size,
                              hipStream_t stream) {
  const float* h   = (const float*)d_in[0];
  const float* Wq  = (const float*)d_in[1];
  const float* bq  = (const float*)d_in[2];
  const float* Wk  = (const float*)d_in[3];
  const float* bk  = (const float*)d_in[4];
  const float* Wv  = (const float*)d_in[5];
  const float* bv  = (const float*)d_in[6];
  const int*   src = (const int*)d_in[7];
  const int*   dst = (const int*)d_in[8];
  const int*   ns  = (const int*)d_in[9];
  float* out = (float*)d_out;

  dim3 grid(NH, NG, 1);   // head fast -> same-graph blocks adjacent (h L2 reuse)
  dim3 block(256, 1, 1);
  hipLaunchKernelGGL(raal_fused_kernel, grid, block, 0, stream,
                     h, Wq, bq, Wk, bk, Wv, bv, src, dst, ns, out);
}

// Round 3
// 727.007 us; speedup vs baseline: 1.3041x; 1.0479x over previous
//
#include <hip/hip_runtime.h>

#define NG    1024
#define NN    64
#define NE    128
#define NH    8
#define ND    32
#define INDIM 256
#define NS_   48
#define EPS_  1e-6
#define BK    16

// ======================= Kernel A: QKV GEMM =======================
// ws layout: [G][H][3][NN][ND] f32, sel: 0=Q 1=K 2=V. Per-thread k-chain is
// ascending k=0..255 fp32 FMA + bias at end — bit-identical to fused kernel.
__global__ __launch_bounds__(256, 4) void qkv_gemm_kernel(
    const float* __restrict__ h,
    const float* __restrict__ Wq, const float* __restrict__ bq,
    const float* __restrict__ Wk, const float* __restrict__ bk,
    const float* __restrict__ Wv, const float* __restrict__ bv,
    float* __restrict__ ws)
{
  const int jt  = blockIdx.x;       // 0..5 : col tile (sel, half)
  const int rt  = blockIdx.y;       // 0..511 : row tile (128 rows = 2 graphs)
  const int tid = threadIdx.x;

  const int sel = jt >> 1;
  const int co  = (jt & 1) * 128;
  const float* W  = (sel == 0) ? Wq : (sel == 1) ? Wk : Wv;
  const float* bs = (sel == 0) ? bq : (sel == 1) ? bk : bv;

  __shared__ float hT[BK][132];   // k-major A tile (+4 pad: 2-way max on stores)
  __shared__ float wT[BK][132];   // k-major B tile

  const int ty = tid >> 4, tx = tid & 15;
  const int r8 = ty * 8, c8 = tx * 8;

  float acc[8][8];
  #pragma unroll
  for (int i = 0; i < 8; ++i)
    #pragma unroll
    for (int j = 0; j < 8; ++j) acc[i][j] = 0.f;

  // loader mapping
  const int ra  = tid >> 1;             // A row 0..127
  const int kof = (tid & 1) * 8;        // A k-offset {0,8}
  const int kb  = tid >> 4;             // B k-row 0..15
  const float* hp0 = h + ((size_t)(rt * 128 + ra)) * INDIM + kof;
  const float* wp0 = W + (size_t)kb * (NH * ND) + co + c8;

  float4 pa0, pa1, pb0, pb1;
  pa0 = *(const float4*)(hp0);
  pa1 = *(const float4*)(hp0 + 4);
  pb0 = *(const float4*)(wp0);
  pb1 = *(const float4*)(wp0 + 4);

  for (int kc = 0; kc < INDIM / BK; ++kc) {
    __syncthreads();
    hT[kof + 0][ra] = pa0.x; hT[kof + 1][ra] = pa0.y;
    hT[kof + 2][ra] = pa0.z; hT[kof + 3][ra] = pa0.w;
    hT[kof + 4][ra] = pa1.x; hT[kof + 5][ra] = pa1.y;
    hT[kof + 6][ra] = pa1.z; hT[kof + 7][ra] = pa1.w;
    *(float4*)&wT[kb][c8]     = pb0;
    *(float4*)&wT[kb][c8 + 4] = pb1;
    __syncthreads();

    if (kc + 1 < INDIM / BK) {
      const int k0n = (kc + 1) * BK;
      pa0 = *(const float4*)(hp0 + k0n);
      pa1 = *(const float4*)(hp0 + k0n + 4);
      pb0 = *(const float4*)(wp0 + (size_t)k0n * (NH * ND));
      pb1 = *(const float4*)(wp0 + (size_t)k0n * (NH * ND) + 4);
    }

    #pragma unroll
    for (int k = 0; k < BK; ++k) {
      float4 a0 = *(const float4*)&hT[k][r8];
      float4 a1 = *(const float4*)&hT[k][r8 + 4];
      float4 b0 = *(const float4*)&wT[k][c8];
      float4 b1 = *(const float4*)&wT[k][c8 + 4];
      const float av[8] = {a0.x,a0.y,a0.z,a0.w,a1.x,a1.y,a1.z,a1.w};
      const float bv8[8] = {b0.x,b0.y,b0.z,b0.w,b1.x,b1.y,b1.z,b1.w};
      #pragma unroll
      for (int i = 0; i < 8; ++i)
        #pragma unroll
        for (int j = 0; j < 8; ++j)
          acc[i][j] += av[i] * bv8[j];
    }
  }

  // epilogue: + bias, write to ws[G][H][3][64][32]
  const int cg = co + c8;               // col within sel's 256
  const int hd = cg >> 5;
  const int d0 = cg & 31;
  float bias8[8];
  #pragma unroll
  for (int j = 0; j < 8; ++j) bias8[j] = bs[cg + j];

  #pragma unroll
  for (int i = 0; i < 8; ++i) {
    const int r = rt * 128 + r8 + i;
    const int g = r >> 6, n = r & 63;
    float* op = ws + ((((size_t)(g * NH + hd)) * 3 + sel) * NN + n) * ND + d0;
    float o0[4], o1[4];
    #pragma unroll
    for (int j = 0; j < 4; ++j) { o0[j] = acc[i][j] + bias8[j]; o1[j] = acc[i][4 + j] + bias8[4 + j]; }
    *(float4*)(op)     = make_float4(o0[0], o0[1], o0[2], o0[3]);
    *(float4*)(op + 4) = make_float4(o1[0], o1[1], o1[2], o1[3]);
  }
}

// ======================= Kernel B: attention =======================
__global__ __launch_bounds__(256, 4) void attn_kernel(
    const float* __restrict__ ws,
    const int* __restrict__ src, const int* __restrict__ dst,
    const int* __restrict__ ns,
    float* __restrict__ out)
{
  const int hd  = blockIdx.x;
  const int g   = blockIdx.y;
  const int tid = threadIdx.x;
  const int ty  = tid >> 4, tx = tid & 15;

  __shared__ union {
    struct { float QT[32][68]; float KT[32][68]; } a;  // 17408 B
    float QK[64][65];                                  // 16640 B (padded: spread banks)
  } uQ;
  __shared__ float Vs[64][36];                         // pad 36: stage-4 banks spread by row
  __shared__ float  score_s[NE];
  __shared__ int    srcs[NE], dsts[NE];
  __shared__ double z_s[NN];
  __shared__ unsigned short elist[NN][64];
  __shared__ int cnt[NN];

  // ---- load Q,K (transposed to k-major) and V from ws ----
  const float* base = ws + ((size_t)(g * NH + hd)) * 3 * (NN * ND);
  {
    const int nr = tid >> 3;            // 0..31
    const int d4 = (tid & 7) * 4;
    #pragma unroll
    for (int half = 0; half < 2; ++half) {
      const int n = half * 32 + nr;
      float4 q = *(const float4*)(base + (size_t)n * ND + d4);
      float4 k = *(const float4*)(base + (size_t)(NN * ND) + (size_t)n * ND + d4);
      float4 v = *(const float4*)(base + (size_t)(2 * NN * ND) + (size_t)n * ND + d4);
      uQ.a.QT[d4 + 0][n] = q.x; uQ.a.QT[d4 + 1][n] = q.y;
      uQ.a.QT[d4 + 2][n] = q.z; uQ.a.QT[d4 + 3][n] = q.w;
      uQ.a.KT[d4 + 0][n] = k.x; uQ.a.KT[d4 + 1][n] = k.y;
      uQ.a.KT[d4 + 2][n] = k.z; uQ.a.KT[d4 + 3][n] = k.w;
      *(float4*)&Vs[n][d4] = v;
    }
  }
  __syncthreads();

  // ---- QK[s][t] = clip(Q[s]·K[t], -5, 5) ----
  {
    const int s0 = ty * 4, t0 = tx * 4;
    float qk[4][4];
    #pragma unroll
    for (int i = 0; i < 4; ++i)
      #pragma unroll
      for (int j = 0; j < 4; ++j) qk[i][j] = 0.f;
    #pragma unroll
    for (int k = 0; k < ND; ++k) {
      float4 qa = *(const float4*)&uQ.a.QT[k][s0];
      float4 kb = *(const float4*)&uQ.a.KT[k][t0];
      qk[0][0] += qa.x * kb.x; qk[0][1] += qa.x * kb.y; qk[0][2] += qa.x * kb.z; qk[0][3] += qa.x * kb.w;
      qk[1][0] += qa.y * kb.x; qk[1][1] += qa.y * kb.y; qk[1][2] += qa.y * kb.z; qk[1][3] += qa.y * kb.w;
      qk[2][0] += qa.z * kb.x; qk[2][1] += qa.z * kb.y; qk[2][2] += qa.z * kb.z; qk[2][3] += qa.z * kb.w;
      qk[3][0] += qa.w * kb.x; qk[3][1] += qa.w * kb.y; qk[3][2] += qa.w * kb.z; qk[3][3] += qa.w * kb.w;
    }
    __syncthreads();   // all QT/KT reads done before QK overwrites region
    #pragma unroll
    for (int i = 0; i < 4; ++i)
      #pragma unroll
      for (int j = 0; j < 4; ++j) {
        float v = qk[i][j];
        v = fminf(5.f, fmaxf(-5.f, v));
        uQ.QK[s0 + i][t0 + j] = v;
      }
  }
  __syncthreads();

  // ---- per-edge score (double den, j-ascending chain) ----
  if (tid < NE) {
    const int e = tid;
    const int s = src[e], dd = dst[e];
    srcs[e] = s; dsts[e] = dd;
    const float num = uQ.QK[s][dd];
    double den = 0.0;
    const int* np_ = ns + (size_t)e * NS_;
    #pragma unroll
    for (int j = 0; j < NS_; ++j) den += (double)uQ.QK[s][np_[j]];
    score_s[e] = (float)((double)num / (den + (double)EPS_));
  }
  __syncthreads();

  // ---- per-node edge list + z (e-ascending double chain) ----
  if (tid < NN) {
    int c = 0; double zz = 0.0;
    for (int e = 0; e < NE; ++e) {
      if (dsts[e] == tid) {
        zz += (double)score_s[e];
        if (c < 64) elist[tid][c] = (unsigned short)e;
        ++c;
      }
    }
    cnt[tid] = (c > 64) ? 64 : c;
    z_s[tid] = zz;
  }
  __syncthreads();

  // ---- weighted segment sum + output ----
  {
    const int n  = tid >> 2;
    const int d0 = (tid & 3) * 8;
    float wvv[8];
    #pragma unroll
    for (int i = 0; i < 8; ++i) wvv[i] = 0.f;
    const int cn = cnt[n];
    for (int c = 0; c < cn; ++c) {
      const int e  = elist[n][c];
      const float sc = score_s[e];
      const int s  = srcs[e];
      float4 v0 = *(const float4*)&Vs[s][d0];
      float4 v1 = *(const float4*)&Vs[s][d0 + 4];
      wvv[0] += sc * v0.x; wvv[1] += sc * v0.y; wvv[2] += sc * v0.z; wvv[3] += sc * v0.w;
      wvv[4] += sc * v1.x; wvv[5] += sc * v1.y; wvv[6] += sc * v1.z; wvv[7] += sc * v1.w;
    }
    const double zz = z_s[n] + (double)EPS_;
    float o[8];
    #pragma unroll
    for (int i = 0; i < 8; ++i) o[i] = (float)((double)wvv[i] / zz);
    float* op = out + (((size_t)(g * NN + n)) * NH + hd) * ND + d0;
    *(float4*)(op)     = make_float4(o[0], o[1], o[2], o[3]);
    *(float4*)(op + 4) = make_float4(o[4], o[5], o[6], o[7]);
  }
}

// ======================= Fallback: R2 fused kernel =======================
__global__ __launch_bounds__(256, 4) void raal_fused_kernel(
    const float* __restrict__ h,
    const float* __restrict__ Wq, const float* __restrict__ bq,
    const float* __restrict__ Wk, const float* __restrict__ bk,
    const float* __restrict__ Wv, const float* __restrict__ bv,
    const int*   __restrict__ src, const int* __restrict__ dst,
    const int*   __restrict__ ns,
    float* __restrict__ out)
{
  const int hd  = blockIdx.x;
  const int g   = blockIdx.y;
  const int tid = threadIdx.x;
  const int ty  = tid >> 4, tx = tid & 15;

  __shared__ union {
    struct { float QT[32][64]; float KT[32][64]; } s2;
    float QK[64][64];
  } uQ;
  __shared__ float Vs[64][32];
  __shared__ union {
    struct { float hT[BK][68]; float wT[BK][100]; } s1;
    struct { float score[NE]; int srcs[NE]; int dsts[NE];
             double z[NN]; unsigned short elist[NN][64]; int cnt[NN]; } s3;
  } uA;

  const int r0 = ty * 4;
  const int c4 = tx * 4;
  const int cv = tx * 2;

  float accqk[4][4], accv[4][2];
  #pragma unroll
  for (int i = 0; i < 4; ++i) {
    #pragma unroll
    for (int j = 0; j < 4; ++j) accqk[i][j] = 0.f;
    accv[i][0] = 0.f; accv[i][1] = 0.f;
  }

  const int lr  = tid >> 2;
  const int lk4 = (tid & 3) * 4;
  const int wr  = ty;
  const int wc  = tx * 2;
  const float* hrow = h + ((size_t)(g * NN + lr)) * INDIM + lk4;
  const size_t wcol = (size_t)hd * ND + wc;

  float4 hv; float2 wq2, wk2, wv2;
  {
    hv  = *(const float4*)(hrow);
    const size_t wro = (size_t)wr * (NH * ND) + wcol;
    wq2 = *(const float2*)(Wq + wro);
    wk2 = *(const float2*)(Wk + wro);
    wv2 = *(const float2*)(Wv + wro);
  }

  for (int kc = 0; kc < INDIM / BK; ++kc) {
    __syncthreads();
    uA.s1.hT[lk4 + 0][lr] = hv.x;
    uA.s1.hT[lk4 + 1][lr] = hv.y;
    uA.s1.hT[lk4 + 2][lr] = hv.z;
    uA.s1.hT[lk4 + 3][lr] = hv.w;
    *(float2*)&uA.s1.wT[wr][ 0 + wc] = wq2;
    *(float2*)&uA.s1.wT[wr][32 + wc] = wk2;
    *(float2*)&uA.s1.wT[wr][64 + wc] = wv2;
    __syncthreads();

    if (kc + 1 < INDIM / BK) {
      const int k0n = (kc + 1) * BK;
      hv  = *(const float4*)(hrow + k0n);
      const size_t wro = (size_t)(k0n + wr) * (NH * ND) + wcol;
      wq2 = *(const float2*)(Wq + wro);
      wk2 = *(const float2*)(Wk + wro);
      wv2 = *(const float2*)(Wv + wro);
    }

    #pragma unroll
    for (int k = 0; k < BK; ++k) {
      float4 a  = *(const float4*)&uA.s1.hT[k][r0];
      float4 b  = *(const float4*)&uA.s1.wT[k][c4];
      float2 bv2 = *(const float2*)&uA.s1.wT[k][64 + cv];
      #pragma unroll
      for (int i = 0; i < 4; ++i) {
        const float ai = (i == 0) ? a.x : (i == 1) ? a.y : (i == 2) ? a.z : a.w;
        accqk[i][0] += ai * b.x;
        accqk[i][1] += ai * b.y;
        accqk[i][2] += ai * b.z;
        accqk[i][3] += ai * b.w;
        accv[i][0]  += ai * bv2.x;
        accv[i][1]  += ai * bv2.y;
      }
    }
  }

  {
    if (tx < 8) {
      #pragma unroll
      for (int j = 0; j < 4; ++j) {
        const int c = c4 + j;
        const float b = bq[hd * ND + c];
        #pragma unroll
        for (int i = 0; i < 4; ++i) uQ.s2.QT[c][r0 + i] = accqk[i][j] + b;
      }
    } else {
      #pragma unroll
      for (int j = 0; j < 4; ++j) {
        const int c = c4 - 32 + j;
        const float b = bk[hd * ND + c];
        #pragma unroll
        for (int i = 0; i < 4; ++i) uQ.s2.KT[c][r0 + i] = accqk[i][j] + b;
      }
    }
    const float b0 = bv[hd * ND + cv], b1 = bv[hd * ND + cv + 1];
    #pragma unroll
    for (int i = 0; i < 4; ++i) {
      Vs[r0 + i][cv]     = accv[i][0] + b0;
      Vs[r0 + i][cv + 1] = accv[i][1] + b1;
    }
  }
  __syncthreads();

  {
    const int s0 = ty * 4, t0 = tx * 4;
    float qk[4][4];
    #pragma unroll
    for (int i = 0; i < 4; ++i)
      #pragma unroll
      for (int j = 0; j < 4; ++j) qk[i][j] = 0.f;
    #pragma unroll
    for (int k = 0; k < ND; ++k) {
      float4 qa = *(const float4*)&uQ.s2.QT[k][s0];
      float4 kb = *(const float4*)&uQ.s2.KT[k][t0];
      qk[0][0] += qa.x * kb.x; qk[0][1] += qa.x * kb.y; qk[0][2] += qa.x * kb.z; qk[0][3] += qa.x * kb.w;
      qk[1][0] += qa.y * kb.x; qk[1][1] += qa.y * kb.y; qk[1][2] += qa.y * kb.z; qk[1][3] += qa.y * kb.w;
      qk[2][0] += qa.z * kb.x; qk[2][1] += qa.z * kb.y; qk[2][2] += qa.z * kb.z; qk[2][3] += qa.z * kb.w;
      qk[3][0] += qa.w * kb.x; qk[3][1] += qa.w * kb.y; qk[3][2] += qa.w * kb.z; qk[3][3] += qa.w * kb.w;
    }
    __syncthreads();
    #pragma unroll
    for (int i = 0; i < 4; ++i)
      #pragma unroll
      for (int j = 0; j < 4; ++j) {
        float v = qk[i][j];
        v = fminf(5.f, fmaxf(-5.f, v));
        uQ.QK[s0 + i][t0 + j] = v;
      }
  }
  __syncthreads();

  if (tid < NE) {
    const int e = tid;
    const int s = src[e], dd = dst[e];
    uA.s3.srcs[e] = s; uA.s3.dsts[e] = dd;
    const float num = uQ.QK[s][dd];
    double den = 0.0;
    const int* np_ = ns + (size_t)e * NS_;
    #pragma unroll
    for (int j = 0; j < NS_; ++j) den += (double)uQ.QK[s][np_[j]];
    uA.s3.score[e] = (float)((double)num / (den + (double)EPS_));
  }
  __syncthreads();

  if (tid < NN) {
    int c = 0; double zz = 0.0;
    for (int e = 0; e < NE; ++e) {
      if (uA.s3.dsts[e] == tid) {
        zz += (double)uA.s3.score[e];
        if (c < 64) uA.s3.elist[tid][c] = (unsigned short)e;
        ++c;
      }
    }
    uA.s3.cnt[tid] = (c > 64) ? 64 : c;
    uA.s3.z[tid]   = zz;
  }
  __syncthreads();

  {
    const int n  = tid >> 2;
    const int d0 = (tid & 3) * 8;
    float wvv[8];
    #pragma unroll
    for (int i = 0; i < 8; ++i) wvv[i] = 0.f;
    const int cn = uA.s3.cnt[n];
    for (int c = 0; c < cn; ++c) {
      const int e  = uA.s3.elist[n][c];
      const float sc = uA.s3.score[e];
      const int s  = uA.s3.srcs[e];
      float4 v0 = *(const float4*)&Vs[s][d0];
      float4 v1 = *(const float4*)&Vs[s][d0 + 4];
      wvv[0] += sc * v0.x; wvv[1] += sc * v0.y; wvv[2] += sc * v0.z; wvv[3] += sc * v0.w;
      wvv[4] += sc * v1.x; wvv[5] += sc * v1.y; wvv[6] += sc * v1.z; wvv[7] += sc * v1.w;
    }
    const double zz = uA.s3.z[n] + (double)EPS_;
    float o[8];
    #pragma unroll
    for (int i = 0; i < 8; ++i) o[i] = (float)((double)wvv[i] / zz);
    float* op = out + (((size_t)(g * NN + n)) * NH + hd) * ND + d0;
    *(float4*)(op)     = make_float4(o[0], o[1], o[2], o[3]);
    *(float4*)(op + 4) = make_float4(o[4], o[5], o[6], o[7]);
  }
}

extern "C" void kernel_launch(void* const* d_in, const int* in_sizes, int n_in,
                              void* d_out, int out_size, void* d_ws, size_t ws_size,
                              hipStream_t stream) {
  const float* h   = (const float*)d_in[0];
  const float* Wq  = (const float*)d_in[1];
  const float* bq  = (const float*)d_in[2];
  const float* Wk  = (const float*)d_in[3];
  const float* bk  = (const float*)d_in[4];
  const float* Wv  = (const float*)d_in[5];
  const float* bv  = (const float*)d_in[6];
  const int*   src = (const int*)d_in[7];
  const int*   dst = (const int*)d_in[8];
  const int*   ns  = (const int*)d_in[9];
  float* out = (float*)d_out;

  const size_t need = (size_t)NG * NH * 3 * NN * ND * sizeof(float);  // 192 MiB
  if (ws_size >= need) {
    float* ws = (float*)d_ws;
    dim3 gA(6, 512, 1), b(256, 1, 1);
    hipLaunchKernelGGL(qkv_gemm_kernel, gA, b, 0, stream,
                       h, Wq, bq, Wk, bk, Wv, bv, ws);
    dim3 gB(NH, NG, 1);
    hipLaunchKernelGGL(attn_kernel, gB, b, 0, stream,
                       ws, src, dst, ns, out);
  } else {
    dim3 g(NH, NG, 1), b(256, 1, 1);
    hipLaunchKernelGGL(raal_fused_kernel, g, b, 0, stream,
                       h, Wq, bq, Wk, bk, Wv, bv, src, dst, ns, out);
  }
}

// Round 4
// 609.806 us; speedup vs baseline: 1.5547x; 1.1922x over previous
//
#include <hip/hip_runtime.h>

#define NG    1024
#define NN    64
#define NE    128
#define NH    8
#define ND    32
#define INDIM 256
#define NS_   48
#define EPS_  1e-6
#define BK    16

// ws: [G][H][3][NN][ND] f32 (192 MiB), then elist u16[NN][64], cnt int[NN]
#define WS_QKV_FLOATS ((size_t)NG * NH * 3 * NN * ND)
#define WS_ELIST_OFF  (WS_QKV_FLOATS * sizeof(float))
#define WS_CNT_OFF    (WS_ELIST_OFF + (size_t)NN * 64 * sizeof(unsigned short))
#define WS_NEED2      (WS_CNT_OFF + (size_t)NN * sizeof(int))

// ======================= Kernel A: QKV GEMM =======================
// 3072 blocks, XCD-grouped: all 6 col-tiles (jt) of a row-tile (rt) land on
// the same XCD so the A tile is fetched from HBM once, then L2-hit.
// Thread tile 16 rows x 4 cols: A-frag LDS reads are wave-broadcast (free),
// B-frag is stride-16B conflict-free b128, stores are full 128B lines.
// Per-element chain: acc over k=0..255 ascending fp32 FMA + bias — identical
// to R3 (bit-exact output).
__global__ __launch_bounds__(256, 4) void qkv_gemm_kernel(
    const float* __restrict__ h,
    const float* __restrict__ Wq, const float* __restrict__ bq,
    const float* __restrict__ Wk, const float* __restrict__ bk,
    const float* __restrict__ Wv, const float* __restrict__ bv,
    float* __restrict__ ws)
{
  const int b    = blockIdx.x;          // 0..3071
  const int xcd  = b & 7;
  const int slot = b >> 3;              // 0..383
  const int rt   = xcd * 64 + slot / 6; // 0..511
  const int jt   = slot % 6;
  const int tid  = threadIdx.x;

  const int sel = jt >> 1;
  const int co  = (jt & 1) * 128;
  const float* W  = (sel == 0) ? Wq : (sel == 1) ? Wk : Wv;
  const float* bs = (sel == 0) ? bq : (sel == 1) ? bk : bv;

  __shared__ float hT[BK][132];   // k-major A tile
  __shared__ float wT[BK][132];   // k-major B tile

  const int ty  = tid >> 5;       // 0..7  -> 16 rows
  const int tx  = tid & 31;       // 0..31 -> 4 cols
  const int r16 = ty * 16;
  const int c4  = tx * 4;

  float acc[16][4];
  #pragma unroll
  for (int i = 0; i < 16; ++i)
    #pragma unroll
    for (int j = 0; j < 4; ++j) acc[i][j] = 0.f;

  // loader mapping (same as R3)
  const int ra  = tid >> 1;             // A row 0..127
  const int kof = (tid & 1) * 8;        // A k-offset {0,8}
  const int kb  = tid >> 4;             // B k-row 0..15
  const int c8w = (tid & 15) * 8;       // B col base
  const float* hp0 = h + ((size_t)(rt * 128 + ra)) * INDIM + kof;
  const float* wp0 = W + (size_t)kb * (NH * ND) + co + c8w;

  float4 pa0, pa1, pb0, pb1;
  pa0 = *(const float4*)(hp0);
  pa1 = *(const float4*)(hp0 + 4);
  pb0 = *(const float4*)(wp0);
  pb1 = *(const float4*)(wp0 + 4);

  for (int kc = 0; kc < INDIM / BK; ++kc) {
    __syncthreads();
    hT[kof + 0][ra] = pa0.x; hT[kof + 1][ra] = pa0.y;
    hT[kof + 2][ra] = pa0.z; hT[kof + 3][ra] = pa0.w;
    hT[kof + 4][ra] = pa1.x; hT[kof + 5][ra] = pa1.y;
    hT[kof + 6][ra] = pa1.z; hT[kof + 7][ra] = pa1.w;
    *(float4*)&wT[kb][c8w]     = pb0;
    *(float4*)&wT[kb][c8w + 4] = pb1;
    __syncthreads();

    if (kc + 1 < INDIM / BK) {
      const int k0n = (kc + 1) * BK;
      pa0 = *(const float4*)(hp0 + k0n);
      pa1 = *(const float4*)(hp0 + k0n + 4);
      pb0 = *(const float4*)(wp0 + (size_t)k0n * (NH * ND));
      pb1 = *(const float4*)(wp0 + (size_t)k0n * (NH * ND) + 4);
    }

    #pragma unroll
    for (int k = 0; k < BK; ++k) {
      float4 a0 = *(const float4*)&hT[k][r16];
      float4 a1 = *(const float4*)&hT[k][r16 + 4];
      float4 a2 = *(const float4*)&hT[k][r16 + 8];
      float4 a3 = *(const float4*)&hT[k][r16 + 12];
      float4 bb = *(const float4*)&wT[k][c4];
      const float av[16] = {a0.x,a0.y,a0.z,a0.w, a1.x,a1.y,a1.z,a1.w,
                            a2.x,a2.y,a2.z,a2.w, a3.x,a3.y,a3.z,a3.w};
      #pragma unroll
      for (int i = 0; i < 16; ++i) {
        acc[i][0] += av[i] * bb.x;
        acc[i][1] += av[i] * bb.y;
        acc[i][2] += av[i] * bb.z;
        acc[i][3] += av[i] * bb.w;
      }
    }
  }

  // epilogue: + bias, full-line stores (lanes 0..7 cover one 128B chunk)
  const int cg = co + c4;               // col within sel's 256
  const int hd = cg >> 5;
  const int d0 = cg & 31;
  float bias4[4];
  #pragma unroll
  for (int j = 0; j < 4; ++j) bias4[j] = bs[cg + j];

  #pragma unroll
  for (int i = 0; i < 16; ++i) {
    const int r = rt * 128 + r16 + i;
    const int g = r >> 6, n = r & 63;
    float* op = ws + ((((size_t)(g * NH + hd)) * 3 + sel) * NN + n) * ND + d0;
    *(float4*)op = make_float4(acc[i][0] + bias4[0], acc[i][1] + bias4[1],
                               acc[i][2] + bias4[2], acc[i][3] + bias4[3]);
  }
}

// ======================= Kernel S: per-node edge lists (g/h-invariant) ====
__global__ void edge_setup_kernel(const int* __restrict__ dst,
                                  unsigned short* __restrict__ elist,
                                  int* __restrict__ cnt)
{
  const int n = threadIdx.x;
  if (n < NN) {
    int c = 0;
    for (int e = 0; e < NE; ++e) {
      if (dst[e] == n) {
        if (c < 64) elist[n * 64 + c] = (unsigned short)e;   // e-ascending
        ++c;
      }
    }
    cnt[n] = (c > 64) ? 64 : c;
  }
}

// ======================= Kernel B: attention =======================
__global__ __launch_bounds__(256, 4) void attn_kernel(
    const float* __restrict__ ws,
    const int* __restrict__ src, const int* __restrict__ dst,
    const int* __restrict__ ns,
    const unsigned short* __restrict__ elist_g, const int* __restrict__ cnt_g,
    float* __restrict__ out)
{
  const int hd  = blockIdx.x;
  const int g   = blockIdx.y;
  const int tid = threadIdx.x;
  const int ty  = tid >> 4, tx = tid & 15;

  __shared__ union {
    struct { float QT[32][68]; float KT[32][68]; } a;
    float QK[64][65];
  } uQ;
  __shared__ float Vs[64][36];
  __shared__ float  score_s[NE];
  __shared__ int    srcs[NE], dsts[NE];
  __shared__ double z_s[NN];
  __shared__ unsigned short elist_l[NN][64];
  __shared__ int cnt_l[NN];

  // ---- load Q,K (k-major) and V from ws ----
  const float* base = ws + ((size_t)(g * NH + hd)) * 3 * (NN * ND);
  {
    const int nr = tid >> 3;
    const int d4 = (tid & 7) * 4;
    #pragma unroll
    for (int half = 0; half < 2; ++half) {
      const int n = half * 32 + nr;
      float4 q = *(const float4*)(base + (size_t)n * ND + d4);
      float4 k = *(const float4*)(base + (size_t)(NN * ND) + (size_t)n * ND + d4);
      float4 v = *(const float4*)(base + (size_t)(2 * NN * ND) + (size_t)n * ND + d4);
      uQ.a.QT[d4 + 0][n] = q.x; uQ.a.QT[d4 + 1][n] = q.y;
      uQ.a.QT[d4 + 2][n] = q.z; uQ.a.QT[d4 + 3][n] = q.w;
      uQ.a.KT[d4 + 0][n] = k.x; uQ.a.KT[d4 + 1][n] = k.y;
      uQ.a.KT[d4 + 2][n] = k.z; uQ.a.KT[d4 + 3][n] = k.w;
      *(float4*)&Vs[n][d4] = v;
    }
  }
  __syncthreads();

  // ---- QK[s][t] = clip(Q[s]·K[t], -5, 5) ----
  {
    const int s0 = ty * 4, t0 = tx * 4;
    float qk[4][4];
    #pragma unroll
    for (int i = 0; i < 4; ++i)
      #pragma unroll
      for (int j = 0; j < 4; ++j) qk[i][j] = 0.f;
    #pragma unroll
    for (int k = 0; k < ND; ++k) {
      float4 qa = *(const float4*)&uQ.a.QT[k][s0];
      float4 kb = *(const float4*)&uQ.a.KT[k][t0];
      qk[0][0] += qa.x * kb.x; qk[0][1] += qa.x * kb.y; qk[0][2] += qa.x * kb.z; qk[0][3] += qa.x * kb.w;
      qk[1][0] += qa.y * kb.x; qk[1][1] += qa.y * kb.y; qk[1][2] += qa.y * kb.z; qk[1][3] += qa.y * kb.w;
      qk[2][0] += qa.z * kb.x; qk[2][1] += qa.z * kb.y; qk[2][2] += qa.z * kb.z; qk[2][3] += qa.z * kb.w;
      qk[3][0] += qa.w * kb.x; qk[3][1] += qa.w * kb.y; qk[3][2] += qa.w * kb.z; qk[3][3] += qa.w * kb.w;
    }
    __syncthreads();
    #pragma unroll
    for (int i = 0; i < 4; ++i)
      #pragma unroll
      for (int j = 0; j < 4; ++j) {
        float v = qk[i][j];
        v = fminf(5.f, fmaxf(-5.f, v));
        uQ.QK[s0 + i][t0 + j] = v;
      }
  }
  __syncthreads();

  // ---- per-edge score (double den, j-ascending chain) ----
  if (tid < NE) {
    const int e = tid;
    const int s = src[e], dd = dst[e];
    srcs[e] = s; dsts[e] = dd;
    const float num = uQ.QK[s][dd];
    double den = 0.0;
    const int* np_ = ns + (size_t)e * NS_;
    #pragma unroll
    for (int j = 0; j < NS_; ++j) den += (double)uQ.QK[s][np_[j]];
    score_s[e] = (float)((double)num / (den + (double)EPS_));
  }
  __syncthreads();

  // ---- per-node z (e-ascending double chain) ----
  if (elist_g != nullptr) {
    if (tid < NN) {
      const int cn = cnt_g[tid];
      double zz = 0.0;
      for (int c = 0; c < cn; ++c)
        zz += (double)score_s[elist_g[tid * 64 + c]];
      z_s[tid] = zz;
    }
  } else {
    if (tid < NN) {
      int c = 0; double zz = 0.0;
      for (int e = 0; e < NE; ++e) {
        if (dsts[e] == tid) {
          zz += (double)score_s[e];
          if (c < 64) elist_l[tid][c] = (unsigned short)e;
          ++c;
        }
      }
      cnt_l[tid] = (c > 64) ? 64 : c;
      z_s[tid] = zz;
    }
  }
  __syncthreads();

  // ---- weighted segment sum + output ----
  {
    const int n  = tid >> 2;
    const int d0 = (tid & 3) * 8;
    float wvv[8];
    #pragma unroll
    for (int i = 0; i < 8; ++i) wvv[i] = 0.f;
    const int cn = (elist_g != nullptr) ? cnt_g[n] : cnt_l[n];
    for (int c = 0; c < cn; ++c) {
      const int e  = (elist_g != nullptr) ? elist_g[n * 64 + c] : elist_l[n][c];
      const float sc = score_s[e];
      const int s  = srcs[e];
      float4 v0 = *(const float4*)&Vs[s][d0];
      float4 v1 = *(const float4*)&Vs[s][d0 + 4];
      wvv[0] += sc * v0.x; wvv[1] += sc * v0.y; wvv[2] += sc * v0.z; wvv[3] += sc * v0.w;
      wvv[4] += sc * v1.x; wvv[5] += sc * v1.y; wvv[6] += sc * v1.z; wvv[7] += sc * v1.w;
    }
    const double zz = z_s[n] + (double)EPS_;
    float o[8];
    #pragma unroll
    for (int i = 0; i < 8; ++i) o[i] = (float)((double)wvv[i] / zz);
    float* op = out + (((size_t)(g * NN + n)) * NH + hd) * ND + d0;
    *(float4*)(op)     = make_float4(o[0], o[1], o[2], o[3]);
    *(float4*)(op + 4) = make_float4(o[4], o[5], o[6], o[7]);
  }
}

// ======================= Fallback: fused kernel (R2) =======================
__global__ __launch_bounds__(256, 4) void raal_fused_kernel(
    const float* __restrict__ h,
    const float* __restrict__ Wq, const float* __restrict__ bq,
    const float* __restrict__ Wk, const float* __restrict__ bk,
    const float* __restrict__ Wv, const float* __restrict__ bv,
    const int*   __restrict__ src, const int* __restrict__ dst,
    const int*   __restrict__ ns,
    float* __restrict__ out)
{
  const int hd  = blockIdx.x;
  const int g   = blockIdx.y;
  const int tid = threadIdx.x;
  const int ty  = tid >> 4, tx = tid & 15;

  __shared__ union {
    struct { float QT[32][64]; float KT[32][64]; } s2;
    float QK[64][64];
  } uQ;
  __shared__ float Vs[64][32];
  __shared__ union {
    struct { float hT[BK][68]; float wT[BK][100]; } s1;
    struct { float score[NE]; int srcs[NE]; int dsts[NE];
             double z[NN]; unsigned short elist[NN][64]; int cnt[NN]; } s3;
  } uA;

  const int r0 = ty * 4;
  const int c4 = tx * 4;
  const int cv = tx * 2;

  float accqk[4][4], accv[4][2];
  #pragma unroll
  for (int i = 0; i < 4; ++i) {
    #pragma unroll
    for (int j = 0; j < 4; ++j) accqk[i][j] = 0.f;
    accv[i][0] = 0.f; accv[i][1] = 0.f;
  }

  const int lr  = tid >> 2;
  const int lk4 = (tid & 3) * 4;
  const int wr  = ty;
  const int wc  = tx * 2;
  const float* hrow = h + ((size_t)(g * NN + lr)) * INDIM + lk4;
  const size_t wcol = (size_t)hd * ND + wc;

  float4 hv; float2 wq2, wk2, wv2;
  {
    hv  = *(const float4*)(hrow);
    const size_t wro = (size_t)wr * (NH * ND) + wcol;
    wq2 = *(const float2*)(Wq + wro);
    wk2 = *(const float2*)(Wk + wro);
    wv2 = *(const float2*)(Wv + wro);
  }

  for (int kc = 0; kc < INDIM / BK; ++kc) {
    __syncthreads();
    uA.s1.hT[lk4 + 0][lr] = hv.x;
    uA.s1.hT[lk4 + 1][lr] = hv.y;
    uA.s1.hT[lk4 + 2][lr] = hv.z;
    uA.s1.hT[lk4 + 3][lr] = hv.w;
    *(float2*)&uA.s1.wT[wr][ 0 + wc] = wq2;
    *(float2*)&uA.s1.wT[wr][32 + wc] = wk2;
    *(float2*)&uA.s1.wT[wr][64 + wc] = wv2;
    __syncthreads();

    if (kc + 1 < INDIM / BK) {
      const int k0n = (kc + 1) * BK;
      hv  = *(const float4*)(hrow + k0n);
      const size_t wro = (size_t)(k0n + wr) * (NH * ND) + wcol;
      wq2 = *(const float2*)(Wq + wro);
      wk2 = *(const float2*)(Wk + wro);
      wv2 = *(const float2*)(Wv + wro);
    }

    #pragma unroll
    for (int k = 0; k < BK; ++k) {
      float4 a  = *(const float4*)&uA.s1.hT[k][r0];
      float4 b  = *(const float4*)&uA.s1.wT[k][c4];
      float2 bv2 = *(const float2*)&uA.s1.wT[k][64 + cv];
      #pragma unroll
      for (int i = 0; i < 4; ++i) {
        const float ai = (i == 0) ? a.x : (i == 1) ? a.y : (i == 2) ? a.z : a.w;
        accqk[i][0] += ai * b.x;
        accqk[i][1] += ai * b.y;
        accqk[i][2] += ai * b.z;
        accqk[i][3] += ai * b.w;
        accv[i][0]  += ai * bv2.x;
        accv[i][1]  += ai * bv2.y;
      }
    }
  }

  {
    if (tx < 8) {
      #pragma unroll
      for (int j = 0; j < 4; ++j) {
        const int c = c4 + j;
        const float b = bq[hd * ND + c];
        #pragma unroll
        for (int i = 0; i < 4; ++i) uQ.s2.QT[c][r0 + i] = accqk[i][j] + b;
      }
    } else {
      #pragma unroll
      for (int j = 0; j < 4; ++j) {
        const int c = c4 - 32 + j;
        const float b = bk[hd * ND + c];
        #pragma unroll
        for (int i = 0; i < 4; ++i) uQ.s2.KT[c][r0 + i] = accqk[i][j] + b;
      }
    }
    const float b0 = bv[hd * ND + cv], b1 = bv[hd * ND + cv + 1];
    #pragma unroll
    for (int i = 0; i < 4; ++i) {
      Vs[r0 + i][cv]     = accv[i][0] + b0;
      Vs[r0 + i][cv + 1] = accv[i][1] + b1;
    }
  }
  __syncthreads();

  {
    const int s0 = ty * 4, t0 = tx * 4;
    float qk[4][4];
    #pragma unroll
    for (int i = 0; i < 4; ++i)
      #pragma unroll
      for (int j = 0; j < 4; ++j) qk[i][j] = 0.f;
    #pragma unroll
    for (int k = 0; k < ND; ++k) {
      float4 qa = *(const float4*)&uQ.s2.QT[k][s0];
      float4 kb = *(const float4*)&uQ.s2.KT[k][t0];
      qk[0][0] += qa.x * kb.x; qk[0][1] += qa.x * kb.y; qk[0][2] += qa.x * kb.z; qk[0][3] += qa.x * kb.w;
      qk[1][0] += qa.y * kb.x; qk[1][1] += qa.y * kb.y; qk[1][2] += qa.y * kb.z; qk[1][3] += qa.y * kb.w;
      qk[2][0] += qa.z * kb.x; qk[2][1] += qa.z * kb.y; qk[2][2] += qa.z * kb.z; qk[2][3] += qa.z * kb.w;
      qk[3][0] += qa.w * kb.x; qk[3][1] += qa.w * kb.y; qk[3][2] += qa.w * kb.z; qk[3][3] += qa.w * kb.w;
    }
    __syncthreads();
    #pragma unroll
    for (int i = 0; i < 4; ++i)
      #pragma unroll
      for (int j = 0; j < 4; ++j) {
        float v = qk[i][j];
        v = fminf(5.f, fmaxf(-5.f, v));
        uQ.QK[s0 + i][t0 + j] = v;
      }
  }
  __syncthreads();

  if (tid < NE) {
    const int e = tid;
    const int s = src[e], dd = dst[e];
    uA.s3.srcs[e] = s; uA.s3.dsts[e] = dd;
    const float num = uQ.QK[s][dd];
    double den = 0.0;
    const int* np_ = ns + (size_t)e * NS_;
    #pragma unroll
    for (int j = 0; j < NS_; ++j) den += (double)uQ.QK[s][np_[j]];
    uA.s3.score[e] = (float)((double)num / (den + (double)EPS_));
  }
  __syncthreads();

  if (tid < NN) {
    int c = 0; double zz = 0.0;
    for (int e = 0; e < NE; ++e) {
      if (uA.s3.dsts[e] == tid) {
        zz += (double)uA.s3.score[e];
        if (c < 64) uA.s3.elist[tid][c] = (unsigned short)e;
        ++c;
      }
    }
    uA.s3.cnt[tid] = (c > 64) ? 64 : c;
    uA.s3.z[tid]   = zz;
  }
  __syncthreads();

  {
    const int n  = tid >> 2;
    const int d0 = (tid & 3) * 8;
    float wvv[8];
    #pragma unroll
    for (int i = 0; i < 8; ++i) wvv[i] = 0.f;
    const int cn = uA.s3.cnt[n];
    for (int c = 0; c < cn; ++c) {
      const int e  = uA.s3.elist[n][c];
      const float sc = uA.s3.score[e];
      const int s  = uA.s3.srcs[e];
      float4 v0 = *(const float4*)&Vs[s][d0];
      float4 v1 = *(const float4*)&Vs[s][d0 + 4];
      wvv[0] += sc * v0.x; wvv[1] += sc * v0.y; wvv[2] += sc * v0.z; wvv[3] += sc * v0.w;
      wvv[4] += sc * v1.x; wvv[5] += sc * v1.y; wvv[6] += sc * v1.z; wvv[7] += sc * v1.w;
    }
    const double zz = uA.s3.z[n] + (double)EPS_;
    float o[8];
    #pragma unroll
    for (int i = 0; i < 8; ++i) o[i] = (float)((double)wvv[i] / zz);
    float* op = out + (((size_t)(g * NN + n)) * NH + hd) * ND + d0;
    *(float4*)(op)     = make_float4(o[0], o[1], o[2], o[3]);
    *(float4*)(op + 4) = make_float4(o[4], o[5], o[6], o[7]);
  }
}

extern "C" void kernel_launch(void* const* d_in, const int* in_sizes, int n_in,
                              void* d_out, int out_size, void* d_ws, size_t ws_size,
                              hipStream_t stream) {
  const float* h   = (const float*)d_in[0];
  const float* Wq  = (const float*)d_in[1];
  const float* bq  = (const float*)d_in[2];
  const float* Wk  = (const float*)d_in[3];
  const float* bk  = (const float*)d_in[4];
  const float* Wv  = (const float*)d_in[5];
  const float* bv  = (const float*)d_in[6];
  const int*   src = (const int*)d_in[7];
  const int*   dst = (const int*)d_in[8];
  const int*   ns  = (const int*)d_in[9];
  float* out = (float*)d_out;

  const size_t need = WS_QKV_FLOATS * sizeof(float);   // 192 MiB
  dim3 b(256, 1, 1);
  if (ws_size >= need) {
    float* ws = (float*)d_ws;
    unsigned short* elist = (unsigned short*)((char*)d_ws + WS_ELIST_OFF);
    int* cnt = (int*)((char*)d_ws + WS_CNT_OFF);
    const bool have_tail = (ws_size >= WS_NEED2);

    hipLaunchKernelGGL(qkv_gemm_kernel, dim3(3072, 1, 1), b, 0, stream,
                       h, Wq, bq, Wk, bk, Wv, bv, ws);
    if (have_tail) {
      hipLaunchKernelGGL(edge_setup_kernel, dim3(1, 1, 1), dim3(64, 1, 1), 0, stream,
                         dst, elist, cnt);
      hipLaunchKernelGGL(attn_kernel, dim3(NH, NG, 1), b, 0, stream,
                         ws, src, dst, ns, elist, cnt, out);
    } else {
      hipLaunchKernelGGL(attn_kernel, dim3(NH, NG, 1), b, 0, stream,
                         ws, src, dst, ns, (const unsigned short*)nullptr,
                         (const int*)nullptr, out);
    }
  } else {
    hipLaunchKernelGGL(raal_fused_kernel, dim3(NH, NG, 1), b, 0, stream,
                       h, Wq, bq, Wk, bk, Wv, bv, src, dst, ns, out);
  }
}

// Round 5
// 545.134 us; speedup vs baseline: 1.7392x; 1.1186x over previous
//
#include <hip/hip_runtime.h>

#define NG    1024
#define NN    64
#define NE    128
#define NH    8
#define ND    32
#define INDIM 256
#define NS_   48
#define EPS_  1e-6
#define BK    16

// ws: [G][H][3][NN][ND] f32 (192 MiB), then elist u16[NN][64], cnt int[NN]
#define WS_QKV_FLOATS ((size_t)NG * NH * 3 * NN * ND)
#define WS_ELIST_OFF  (WS_QKV_FLOATS * sizeof(float))
#define WS_CNT_OFF    (WS_ELIST_OFF + (size_t)NN * 64 * sizeof(unsigned short))
#define WS_NEED2      (WS_CNT_OFF + (size_t)NN * sizeof(int))

// ======================= Kernel A: QKV GEMM v2 =======================
// 1536 blocks (8 XCD groups x 64 row-tiles x 3 sel), block tile 128x256.
// Thread tile 16x8: mn=128 > ~6(m+n)=144 borderline -> T_lds/T_valu = 1.125
// (vs 1.875 in R4). All LDS access conflict-free:
//   - A-frag: 4x b128 broadcast (2 distinct addrs/wave = free 2-way)
//   - B-frag: 2x b128 at consecutive 16B (tx*4 and 128+tx*4) — canonical
//   - B-stage: consecutive b128 stores; A-stage: scalar, 2-way only
// Per-element chain: k=0..255 ascending fp32 FMA + bias — bit-identical to R4.
__global__ __launch_bounds__(256, 2) void qkv_gemm_kernel(
    const float* __restrict__ h,
    const float* __restrict__ Wq, const float* __restrict__ bq,
    const float* __restrict__ Wk, const float* __restrict__ bk,
    const float* __restrict__ Wv, const float* __restrict__ bv,
    float* __restrict__ ws)
{
  const int b    = blockIdx.x;          // 0..1535
  const int xcd  = b & 7;
  const int slot = b >> 3;              // 0..191
  const int rt   = xcd * 64 + slot / 3; // 0..511
  const int sel  = slot % 3;            // 0=Q 1=K 2=V (full 256-col slab)
  const int tid  = threadIdx.x;

  const float* W  = (sel == 0) ? Wq : (sel == 1) ? Wk : Wv;
  const float* bs = (sel == 0) ? bq : (sel == 1) ? bk : bv;

  __shared__ float hT[BK][132];   // k-major A tile (128 rows)
  __shared__ float wT[BK][260];   // k-major B tile (256 cols)

  const int ty  = tid >> 5;       // 0..7  -> rows r16..r16+15
  const int tx  = tid & 31;       // 0..31
  const int r16 = ty * 16;
  const int ca  = tx * 4;         // col group A: 0..124
  const int cb  = 128 + tx * 4;   // col group B: 128..252

  float acc[16][8];
  #pragma unroll
  for (int i = 0; i < 16; ++i)
    #pragma unroll
    for (int j = 0; j < 8; ++j) acc[i][j] = 0.f;

  // loader mapping
  const int ra  = tid >> 1;             // A row 0..127
  const int kof = (tid & 1) * 8;        // A k-offset {0,8}
  const int kb2 = tid >> 6;             // B base k-row 0..3 (wave-uniform)
  const int c4  = (tid & 63) * 4;       // B col 0..252 (consecutive per wave)
  const float* hp0 = h + ((size_t)(rt * 128 + ra)) * INDIM + kof;
  const float* wp0 = W + (size_t)kb2 * (NH * ND) + c4;

  float4 pa0, pa1, pb[4];
  pa0 = *(const float4*)(hp0);
  pa1 = *(const float4*)(hp0 + 4);
  #pragma unroll
  for (int j = 0; j < 4; ++j)
    pb[j] = *(const float4*)(wp0 + (size_t)(4 * j) * (NH * ND));

  for (int kc = 0; kc < INDIM / BK; ++kc) {
    __syncthreads();
    hT[kof + 0][ra] = pa0.x; hT[kof + 1][ra] = pa0.y;
    hT[kof + 2][ra] = pa0.z; hT[kof + 3][ra] = pa0.w;
    hT[kof + 4][ra] = pa1.x; hT[kof + 5][ra] = pa1.y;
    hT[kof + 6][ra] = pa1.z; hT[kof + 7][ra] = pa1.w;
    #pragma unroll
    for (int j = 0; j < 4; ++j)
      *(float4*)&wT[kb2 + 4 * j][c4] = pb[j];
    __syncthreads();

    if (kc + 1 < INDIM / BK) {
      const int k0n = (kc + 1) * BK;
      pa0 = *(const float4*)(hp0 + k0n);
      pa1 = *(const float4*)(hp0 + k0n + 4);
      #pragma unroll
      for (int j = 0; j < 4; ++j)
        pb[j] = *(const float4*)(wp0 + (size_t)(k0n + 4 * j) * (NH * ND));
    }

    #pragma unroll
    for (int k = 0; k < BK; ++k) {
      float4 a0 = *(const float4*)&hT[k][r16];
      float4 a1 = *(const float4*)&hT[k][r16 + 4];
      float4 a2 = *(const float4*)&hT[k][r16 + 8];
      float4 a3 = *(const float4*)&hT[k][r16 + 12];
      float4 b0 = *(const float4*)&wT[k][ca];
      float4 b1 = *(const float4*)&wT[k][cb];
      const float av[16] = {a0.x,a0.y,a0.z,a0.w, a1.x,a1.y,a1.z,a1.w,
                            a2.x,a2.y,a2.z,a2.w, a3.x,a3.y,a3.z,a3.w};
      #pragma unroll
      for (int i = 0; i < 16; ++i) {
        acc[i][0] += av[i] * b0.x;
        acc[i][1] += av[i] * b0.y;
        acc[i][2] += av[i] * b0.z;
        acc[i][3] += av[i] * b0.w;
        acc[i][4] += av[i] * b1.x;
        acc[i][5] += av[i] * b1.y;
        acc[i][6] += av[i] * b1.z;
        acc[i][7] += av[i] * b1.w;
      }
    }
  }

  // epilogue: + bias, full-line float4 stores into ws[G][H][3][64][32]
  const int hda = ca >> 5, d0a = ca & 31;
  const int hdb = cb >> 5, d0b = cb & 31;
  float ba4[4], bb4[4];
  #pragma unroll
  for (int j = 0; j < 4; ++j) { ba4[j] = bs[ca + j]; bb4[j] = bs[cb + j]; }

  #pragma unroll
  for (int i = 0; i < 16; ++i) {
    const int r = rt * 128 + r16 + i;
    const int g = r >> 6, n = r & 63;
    float* opa = ws + ((((size_t)(g * NH + hda)) * 3 + sel) * NN + n) * ND + d0a;
    float* opb = ws + ((((size_t)(g * NH + hdb)) * 3 + sel) * NN + n) * ND + d0b;
    *(float4*)opa = make_float4(acc[i][0] + ba4[0], acc[i][1] + ba4[1],
                                acc[i][2] + ba4[2], acc[i][3] + ba4[3]);
    *(float4*)opb = make_float4(acc[i][4] + bb4[0], acc[i][5] + bb4[1],
                                acc[i][6] + bb4[2], acc[i][7] + bb4[3]);
  }
}

// ======================= Kernel S: per-node edge lists (g/h-invariant) ====
__global__ void edge_setup_kernel(const int* __restrict__ dst,
                                  unsigned short* __restrict__ elist,
                                  int* __restrict__ cnt)
{
  const int n = threadIdx.x;
  if (n < NN) {
    int c = 0;
    for (int e = 0; e < NE; ++e) {
      if (dst[e] == n) {
        if (c < 64) elist[n * 64 + c] = (unsigned short)e;   // e-ascending
        ++c;
      }
    }
    cnt[n] = (c > 64) ? 64 : c;
  }
}

// ======================= Kernel B: attention =======================
__global__ __launch_bounds__(256, 5) void attn_kernel(
    const float* __restrict__ ws,
    const int* __restrict__ src, const int* __restrict__ dst,
    const int* __restrict__ ns,
    const unsigned short* __restrict__ elist_g, const int* __restrict__ cnt_g,
    float* __restrict__ out)
{
  const int hd  = blockIdx.x;
  const int g   = blockIdx.y;
  const int tid = threadIdx.x;
  const int ty  = tid >> 4, tx = tid & 15;

  __shared__ union {
    struct { float QT[32][68]; float KT[32][68]; } a;
    float QK[64][65];
  } uQ;
  __shared__ float Vs[64][36];
  __shared__ float  score_s[NE];
  __shared__ int    srcs[NE], dsts[NE];
  __shared__ double z_s[NN];
  // total ~28.7 KB -> 5 blocks/CU

  // ---- load Q,K (k-major) and V from ws ----
  const float* base = ws + ((size_t)(g * NH + hd)) * 3 * (NN * ND);
  {
    const int nr = tid >> 3;
    const int d4 = (tid & 7) * 4;
    #pragma unroll
    for (int half = 0; half < 2; ++half) {
      const int n = half * 32 + nr;
      float4 q = *(const float4*)(base + (size_t)n * ND + d4);
      float4 k = *(const float4*)(base + (size_t)(NN * ND) + (size_t)n * ND + d4);
      float4 v = *(const float4*)(base + (size_t)(2 * NN * ND) + (size_t)n * ND + d4);
      uQ.a.QT[d4 + 0][n] = q.x; uQ.a.QT[d4 + 1][n] = q.y;
      uQ.a.QT[d4 + 2][n] = q.z; uQ.a.QT[d4 + 3][n] = q.w;
      uQ.a.KT[d4 + 0][n] = k.x; uQ.a.KT[d4 + 1][n] = k.y;
      uQ.a.KT[d4 + 2][n] = k.z; uQ.a.KT[d4 + 3][n] = k.w;
      *(float4*)&Vs[n][d4] = v;
    }
  }
  __syncthreads();

  // ---- QK[s][t] = clip(Q[s]·K[t], -5, 5) ----
  {
    const int s0 = ty * 4, t0 = tx * 4;
    float qk[4][4];
    #pragma unroll
    for (int i = 0; i < 4; ++i)
      #pragma unroll
      for (int j = 0; j < 4; ++j) qk[i][j] = 0.f;
    #pragma unroll
    for (int k = 0; k < ND; ++k) {
      float4 qa = *(const float4*)&uQ.a.QT[k][s0];
      float4 kb = *(const float4*)&uQ.a.KT[k][t0];
      qk[0][0] += qa.x * kb.x; qk[0][1] += qa.x * kb.y; qk[0][2] += qa.x * kb.z; qk[0][3] += qa.x * kb.w;
      qk[1][0] += qa.y * kb.x; qk[1][1] += qa.y * kb.y; qk[1][2] += qa.y * kb.z; qk[1][3] += qa.y * kb.w;
      qk[2][0] += qa.z * kb.x; qk[2][1] += qa.z * kb.y; qk[2][2] += qa.z * kb.z; qk[2][3] += qa.z * kb.w;
      qk[3][0] += qa.w * kb.x; qk[3][1] += qa.w * kb.y; qk[3][2] += qa.w * kb.z; qk[3][3] += qa.w * kb.w;
    }
    __syncthreads();   // all QT/KT reads done before QK overwrites region
    #pragma unroll
    for (int i = 0; i < 4; ++i)
      #pragma unroll
      for (int j = 0; j < 4; ++j) {
        float v = qk[i][j];
        v = fminf(5.f, fmaxf(-5.f, v));
        uQ.QK[s0 + i][t0 + j] = v;
      }
  }
  __syncthreads();

  // ---- per-edge score (double den, j-ascending chain) ----
  if (tid < NE) {
    const int e = tid;
    const int s = src[e], dd = dst[e];
    srcs[e] = s; dsts[e] = dd;
    const float num = uQ.QK[s][dd];
    double den = 0.0;
    const int* np_ = ns + (size_t)e * NS_;
    #pragma unroll
    for (int j = 0; j < NS_; ++j) den += (double)uQ.QK[s][np_[j]];
    score_s[e] = (float)((double)num / (den + (double)EPS_));
  }
  __syncthreads();

  // ---- per-node z (e-ascending double chain via precomputed edge lists) ----
  if (tid < NN) {
    const int cn = cnt_g[tid];
    double zz = 0.0;
    for (int c = 0; c < cn; ++c)
      zz += (double)score_s[elist_g[tid * 64 + c]];
    z_s[tid] = zz;
  }
  __syncthreads();

  // ---- weighted segment sum + output ----
  {
    const int n  = tid >> 2;
    const int d0 = (tid & 3) * 8;
    float wvv[8];
    #pragma unroll
    for (int i = 0; i < 8; ++i) wvv[i] = 0.f;
    const int cn = cnt_g[n];
    for (int c = 0; c < cn; ++c) {
      const int e  = elist_g[n * 64 + c];
      const float sc = score_s[e];
      const int s  = srcs[e];
      float4 v0 = *(const float4*)&Vs[s][d0];
      float4 v1 = *(const float4*)&Vs[s][d0 + 4];
      wvv[0] += sc * v0.x; wvv[1] += sc * v0.y; wvv[2] += sc * v0.z; wvv[3] += sc * v0.w;
      wvv[4] += sc * v1.x; wvv[5] += sc * v1.y; wvv[6] += sc * v1.z; wvv[7] += sc * v1.w;
    }
    const double zz = z_s[n] + (double)EPS_;
    float o[8];
    #pragma unroll
    for (int i = 0; i < 8; ++i) o[i] = (float)((double)wvv[i] / zz);
    float* op = out + (((size_t)(g * NN + n)) * NH + hd) * ND + d0;
    *(float4*)(op)     = make_float4(o[0], o[1], o[2], o[3]);
    *(float4*)(op + 4) = make_float4(o[4], o[5], o[6], o[7]);
  }
}

// ======================= Fallback: fused kernel (R2) =======================
__global__ __launch_bounds__(256, 4) void raal_fused_kernel(
    const float* __restrict__ h,
    const float* __restrict__ Wq, const float* __restrict__ bq,
    const float* __restrict__ Wk, const float* __restrict__ bk,
    const float* __restrict__ Wv, const float* __restrict__ bv,
    const int*   __restrict__ src, const int* __restrict__ dst,
    const int*   __restrict__ ns,
    float* __restrict__ out)
{
  const int hd  = blockIdx.x;
  const int g   = blockIdx.y;
  const int tid = threadIdx.x;
  const int ty  = tid >> 4, tx = tid & 15;

  __shared__ union {
    struct { float QT[32][64]; float KT[32][64]; } s2;
    float QK[64][64];
  } uQ;
  __shared__ float Vs[64][32];
  __shared__ union {
    struct { float hT[BK][68]; float wT[BK][100]; } s1;
    struct { float score[NE]; int srcs[NE]; int dsts[NE];
             double z[NN]; unsigned short elist[NN][64]; int cnt[NN]; } s3;
  } uA;

  const int r0 = ty * 4;
  const int c4 = tx * 4;
  const int cv = tx * 2;

  float accqk[4][4], accv[4][2];
  #pragma unroll
  for (int i = 0; i < 4; ++i) {
    #pragma unroll
    for (int j = 0; j < 4; ++j) accqk[i][j] = 0.f;
    accv[i][0] = 0.f; accv[i][1] = 0.f;
  }

  const int lr  = tid >> 2;
  const int lk4 = (tid & 3) * 4;
  const int wr  = ty;
  const int wc  = tx * 2;
  const float* hrow = h + ((size_t)(g * NN + lr)) * INDIM + lk4;
  const size_t wcol = (size_t)hd * ND + wc;

  float4 hv; float2 wq2, wk2, wv2;
  {
    hv  = *(const float4*)(hrow);
    const size_t wro = (size_t)wr * (NH * ND) + wcol;
    wq2 = *(const float2*)(Wq + wro);
    wk2 = *(const float2*)(Wk + wro);
    wv2 = *(const float2*)(Wv + wro);
  }

  for (int kc = 0; kc < INDIM / BK; ++kc) {
    __syncthreads();
    uA.s1.hT[lk4 + 0][lr] = hv.x;
    uA.s1.hT[lk4 + 1][lr] = hv.y;
    uA.s1.hT[lk4 + 2][lr] = hv.z;
    uA.s1.hT[lk4 + 3][lr] = hv.w;
    *(float2*)&uA.s1.wT[wr][ 0 + wc] = wq2;
    *(float2*)&uA.s1.wT[wr][32 + wc] = wk2;
    *(float2*)&uA.s1.wT[wr][64 + wc] = wv2;
    __syncthreads();

    if (kc + 1 < INDIM / BK) {
      const int k0n = (kc + 1) * BK;
      hv  = *(const float4*)(hrow + k0n);
      const size_t wro = (size_t)(k0n + wr) * (NH * ND) + wcol;
      wq2 = *(const float2*)(Wq + wro);
      wk2 = *(const float2*)(Wk + wro);
      wv2 = *(const float2*)(Wv + wro);
    }

    #pragma unroll
    for (int k = 0; k < BK; ++k) {
      float4 a  = *(const float4*)&uA.s1.hT[k][r0];
      float4 b  = *(const float4*)&uA.s1.wT[k][c4];
      float2 bv2 = *(const float2*)&uA.s1.wT[k][64 + cv];
      #pragma unroll
      for (int i = 0; i < 4; ++i) {
        const float ai = (i == 0) ? a.x : (i == 1) ? a.y : (i == 2) ? a.z : a.w;
        accqk[i][0] += ai * b.x;
        accqk[i][1] += ai * b.y;
        accqk[i][2] += ai * b.z;
        accqk[i][3] += ai * b.w;
        accv[i][0]  += ai * bv2.x;
        accv[i][1]  += ai * bv2.y;
      }
    }
  }

  {
    if (tx < 8) {
      #pragma unroll
      for (int j = 0; j < 4; ++j) {
        const int c = c4 + j;
        const float b = bq[hd * ND + c];
        #pragma unroll
        for (int i = 0; i < 4; ++i) uQ.s2.QT[c][r0 + i] = accqk[i][j] + b;
      }
    } else {
      #pragma unroll
      for (int j = 0; j < 4; ++j) {
        const int c = c4 - 32 + j;
        const float b = bk[hd * ND + c];
        #pragma unroll
        for (int i = 0; i < 4; ++i) uQ.s2.KT[c][r0 + i] = accqk[i][j] + b;
      }
    }
    const float b0 = bv[hd * ND + cv], b1 = bv[hd * ND + cv + 1];
    #pragma unroll
    for (int i = 0; i < 4; ++i) {
      Vs[r0 + i][cv]     = accv[i][0] + b0;
      Vs[r0 + i][cv + 1] = accv[i][1] + b1;
    }
  }
  __syncthreads();

  {
    const int s0 = ty * 4, t0 = tx * 4;
    float qk[4][4];
    #pragma unroll
    for (int i = 0; i < 4; ++i)
      #pragma unroll
      for (int j = 0; j < 4; ++j) qk[i][j] = 0.f;
    #pragma unroll
    for (int k = 0; k < ND; ++k) {
      float4 qa = *(const float4*)&uQ.s2.QT[k][s0];
      float4 kb = *(const float4*)&uQ.s2.KT[k][t0];
      qk[0][0] += qa.x * kb.x; qk[0][1] += qa.x * kb.y; qk[0][2] += qa.x * kb.z; qk[0][3] += qa.x * kb.w;
      qk[1][0] += qa.y * kb.x; qk[1][1] += qa.y * kb.y; qk[1][2] += qa.y * kb.z; qk[1][3] += qa.y * kb.w;
      qk[2][0] += qa.z * kb.x; qk[2][1] += qa.z * kb.y; qk[2][2] += qa.z * kb.z; qk[2][3] += qa.z * kb.w;
      qk[3][0] += qa.w * kb.x; qk[3][1] += qa.w * kb.y; qk[3][2] += qa.w * kb.z; qk[3][3] += qa.w * kb.w;
    }
    __syncthreads();
    #pragma unroll
    for (int i = 0; i < 4; ++i)
      #pragma unroll
      for (int j = 0; j < 4; ++j) {
        float v = qk[i][j];
        v = fminf(5.f, fmaxf(-5.f, v));
        uQ.QK[s0 + i][t0 + j] = v;
      }
  }
  __syncthreads();

  if (tid < NE) {
    const int e = tid;
    const int s = src[e], dd = dst[e];
    uA.s3.srcs[e] = s; uA.s3.dsts[e] = dd;
    const float num = uQ.QK[s][dd];
    double den = 0.0;
    const int* np_ = ns + (size_t)e * NS_;
    #pragma unroll
    for (int j = 0; j < NS_; ++j) den += (double)uQ.QK[s][np_[j]];
    uA.s3.score[e] = (float)((double)num / (den + (double)EPS_));
  }
  __syncthreads();

  if (tid < NN) {
    int c = 0; double zz = 0.0;
    for (int e = 0; e < NE; ++e) {
      if (uA.s3.dsts[e] == tid) {
        zz += (double)uA.s3.score[e];
        if (c < 64) uA.s3.elist[tid][c] = (unsigned short)e;
        ++c;
      }
    }
    uA.s3.cnt[tid] = (c > 64) ? 64 : c;
    uA.s3.z[tid]   = zz;
  }
  __syncthreads();

  {
    const int n  = tid >> 2;
    const int d0 = (tid & 3) * 8;
    float wvv[8];
    #pragma unroll
    for (int i = 0; i < 8; ++i) wvv[i] = 0.f;
    const int cn = uA.s3.cnt[n];
    for (int c = 0; c < cn; ++c) {
      const int e  = uA.s3.elist[n][c];
      const float sc = uA.s3.score[e];
      const int s  = uA.s3.srcs[e];
      float4 v0 = *(const float4*)&Vs[s][d0];
      float4 v1 = *(const float4*)&Vs[s][d0 + 4];
      wvv[0] += sc * v0.x; wvv[1] += sc * v0.y; wvv[2] += sc * v0.z; wvv[3] += sc * v0.w;
      wvv[4] += sc * v1.x; wvv[5] += sc * v1.y; wvv[6] += sc * v1.z; wvv[7] += sc * v1.w;
    }
    const double zz = uA.s3.z[n] + (double)EPS_;
    float o[8];
    #pragma unroll
    for (int i = 0; i < 8; ++i) o[i] = (float)((double)wvv[i] / zz);
    float* op = out + (((size_t)(g * NN + n)) * NH + hd) * ND + d0;
    *(float4*)(op)     = make_float4(o[0], o[1], o[2], o[3]);
    *(float4*)(op + 4) = make_float4(o[4], o[5], o[6], o[7]);
  }
}

extern "C" void kernel_launch(void* const* d_in, const int* in_sizes, int n_in,
                              void* d_out, int out_size, void* d_ws, size_t ws_size,
                              hipStream_t stream) {
  const float* h   = (const float*)d_in[0];
  const float* Wq  = (const float*)d_in[1];
  const float* bq  = (const float*)d_in[2];
  const float* Wk  = (const float*)d_in[3];
  const float* bk  = (const float*)d_in[4];
  const float* Wv  = (const float*)d_in[5];
  const float* bv  = (const float*)d_in[6];
  const int*   src = (const int*)d_in[7];
  const int*   dst = (const int*)d_in[8];
  const int*   ns  = (const int*)d_in[9];
  float* out = (float*)d_out;

  dim3 b(256, 1, 1);
  if (ws_size >= WS_NEED2) {
    float* ws = (float*)d_ws;
    unsigned short* elist = (unsigned short*)((char*)d_ws + WS_ELIST_OFF);
    int* cnt = (int*)((char*)d_ws + WS_CNT_OFF);

    hipLaunchKernelGGL(qkv_gemm_kernel, dim3(1536, 1, 1), b, 0, stream,
                       h, Wq, bq, Wk, bk, Wv, bv, ws);
    hipLaunchKernelGGL(edge_setup_kernel, dim3(1, 1, 1), dim3(64, 1, 1), 0, stream,
                       dst, elist, cnt);
    hipLaunchKernelGGL(attn_kernel, dim3(NH, NG, 1), b, 0, stream,
                       ws, src, dst, ns, elist, cnt, out);
  } else {
    hipLaunchKernelGGL(raal_fused_kernel, dim3(NH, NG, 1), b, 0, stream,
                       h, Wq, bq, Wk, bk, Wv, bv, src, dst, ns, out);
  }
}